// Round 4
// baseline (343.624 us; speedup 1.0000x reference)
//
#include <hip/hip_runtime.h>

// gemm_bt (PV / out-proj): 256x128 tile, BK=64, 8 waves (4x2), 3-deep pipeline.
#define BM 256
#define BN 128
#define BK 64
#define NBUF 3
#define BUFELEMS ((BM + BN) * BK)   // bf16 elems per K-tile buffer (A then B)

typedef __bf16 bf16x8 __attribute__((ext_vector_type(8)));
typedef __bf16 bf16x4 __attribute__((ext_vector_type(4)));
typedef float f32x4 __attribute__((ext_vector_type(4)));
typedef __bf16 bf16_t;

#define MFMA16(a, b, c) __builtin_amdgcn_mfma_f32_16x16x32_bf16((a), (b), (c), 0, 0, 0)

__device__ __forceinline__ void gl_lds16(const void* g, void* l) {
    __builtin_amdgcn_global_load_lds(
        (const __attribute__((address_space(1))) void*)g,
        (__attribute__((address_space(3))) void*)l, 16, 0, 0);
}
// raw barrier with compiler memory fence: does NOT drain vmcnt (that's the point)
__device__ __forceinline__ void barrier_mem() {
    asm volatile("s_barrier" ::: "memory");
}

// fp32 -> bf16 conversion for hid + 4 weight matrices in ONE launch.
__global__ __launch_bounds__(256)
void cvt_all_kernel(const float* __restrict__ hid,
                    const float* __restrict__ w0, const float* __restrict__ w1,
                    const float* __restrict__ w2, const float* __restrict__ w3,
                    bf16_t* __restrict__ hidb, bf16_t* __restrict__ wb)
{
    const int bid = blockIdx.x;
    const float* src;
    bf16_t* dst;
    size_t off;
    if (bid < 8192) {
        src = hid; dst = hidb; off = (size_t)bid * 1024;
    } else {
        const int i = (bid - 8192) >> 10;
        src = (i == 0) ? w0 : (i == 1) ? w1 : (i == 2) ? w2 : w3;
        dst = wb + (size_t)i * 1024 * 1024;
        off = (size_t)((bid - 8192) & 1023) * 1024;
    }
    const size_t idx = off + threadIdx.x * 4;
    const float4 v = *(const float4*)(src + idx);
    bf16x4 o;
    o[0] = (__bf16)v.x; o[1] = (__bf16)v.y;
    o[2] = (__bf16)v.z; o[3] = (__bf16)v.w;
    *(bf16x4*)(dst + idx) = o;
}

// ---------------------------------------------------------------------------
// gemm8 v2: 256x256 tile, BK=64, 8 waves (2m x 4n), per-wave 128x64 output.
// (m-half, k-half) quadrant phases, 4 per K-tile:
//   Q1=(m0,k0): read 4 A-frags + 4 B-frags (8 ds_read_b128)
//   Q2=(m1,k0): read 4 A-frags (B reused in regs)
//   Q3=(m0,k1): read 4 A + 4 B
//   Q4=(m1,k1): read 4 A
// LDS: A[2buf][2kh][256x32] + B[2buf][2kh][256x32] = 128 KiB. 64 B rows make
// each fragment read a bijection onto a contiguous 1024 B region ->
// conflict-free with NO swizzle; staging is plain linear.
// Stage ledger (1 half-tile = 2 gl_lds/thread per phase, issued AFTER the
// phase barrier so the dest region is provably free):
//   Q1(t): A(t+1)k1   Q2(t): B(t+1)k1   Q3(t): A(t+2)k0   Q4(t): B(t+2)k0
// -> prefetch distance 5-6 phases. Counted waits (derived, never 0 in
// steady state): vmcnt(8) before Q1 and Q3 barriers; tail: 4 then 0.
// MODE 0: QKV fused over z (z=2 -> vT transposed store); MODE 3: plain store.
// Requires: num_m_tiles % 8 == 0 (GM=8 XCD grouping), K % 128 == 0, NT >= 3.
// ---------------------------------------------------------------------------
#define ABASE(b, k) (((b) * 2 + (k)) * 8192)
#define BBASE(b, k) (32768 + ((b) * 2 + (k)) * 8192)

#define QP(BUF, MH, KH, RDB, DOST, SRC, DST, VM)                              \
  do {                                                                        \
    if ((VM) == 8)      asm volatile("s_waitcnt vmcnt(8)" ::: "memory");      \
    else if ((VM) == 4) asm volatile("s_waitcnt vmcnt(4)" ::: "memory");      \
    else if ((VM) == 0) asm volatile("s_waitcnt vmcnt(0)" ::: "memory");      \
    barrier_mem();                                                            \
    bf16x8 af0 = rdA(BUF, KH, (MH) * 4 + 0);                                  \
    bf16x8 af1 = rdA(BUF, KH, (MH) * 4 + 1);                                  \
    bf16x8 af2 = rdA(BUF, KH, (MH) * 4 + 2);                                  \
    bf16x8 af3 = rdA(BUF, KH, (MH) * 4 + 3);                                  \
    if (RDB) {                                                                \
      bfr[0] = rdB(BUF, KH, 0); bfr[1] = rdB(BUF, KH, 1);                     \
      bfr[2] = rdB(BUF, KH, 2); bfr[3] = rdB(BUF, KH, 3);                     \
    }                                                                         \
    if (DOST) issueHalf((SRC), (DST));                                        \
    asm volatile("s_waitcnt lgkmcnt(0)" ::: "memory");                        \
    __builtin_amdgcn_s_setprio(1);                                            \
    _Pragma("unroll")                                                         \
    for (int nf = 0; nf < 4; ++nf) {                                          \
      acc[(MH) * 4 + 0][nf] = MFMA16(af0, bfr[nf], acc[(MH) * 4 + 0][nf]);    \
      acc[(MH) * 4 + 1][nf] = MFMA16(af1, bfr[nf], acc[(MH) * 4 + 1][nf]);    \
      acc[(MH) * 4 + 2][nf] = MFMA16(af2, bfr[nf], acc[(MH) * 4 + 2][nf]);    \
      acc[(MH) * 4 + 3][nf] = MFMA16(af3, bfr[nf], acc[(MH) * 4 + 3][nf]);    \
    }                                                                         \
    __builtin_amdgcn_s_setprio(0);                                            \
  } while (0)

template <int MODE>
__global__ __launch_bounds__(512, 2)
void gemm8(const bf16_t* __restrict__ A, const bf16_t* __restrict__ Bw,
           const float* __restrict__ bias, const float* __restrict__ bias2,
           const float* __restrict__ bias3,
           bf16_t* __restrict__ C, bf16_t* __restrict__ C2,
           int M, int N, int K,
           long long sAz, long long sBz, long long sCz,
           int Sdim, int DHdim)
{
    const int bz = blockIdx.z;
    const float* bi = bias;
    if (MODE == 0) {
        Bw += (long long)bz * N * K;        // Wq | Wk | Wv contiguous
        bi = (bz == 0) ? bias : (bz == 1 ? bias2 : bias3);
        if (bz < 2) C += (long long)bz * sCz;
    } else {
        A += (long long)bz * sAz;
        Bw += (long long)bz * sBz;
        C += (long long)bz * sCz;
    }
    // grouped XCD-aware decode (GM=8) over 256x256 tiles
    const int num_n = N >> 8;
    const int pid = blockIdx.x;
    const int group = 8 * num_n;
    const int g = pid / group;
    const int m0 = (g * 8 + (pid % 8)) * 256;
    const int n0 = ((pid % group) >> 3) * 256;

    const int tid = threadIdx.x;
    const int w = tid >> 6;          // wave 0..7
    const int lane = tid & 63;
    const int wr = w >> 2;           // 0..1 : 128-row half
    const int wc = w & 3;            // 0..3 : 64-col quarter
    const int frow = lane & 15;
    const int fchunk = lane >> 4;    // 0..3 (8-elem chunk within 32-k half)

    __shared__ bf16_t smem[8 * 8192];       // 128 KiB

    // staging: thread t covers row (t>>2) of a 128-row half, 16B chunk (t&3).
    // Linear both sides (no swizzle needed with 64B rows).
    const size_t soff = (size_t)(tid >> 2) * K + (size_t)(tid & 3) * 8;

    const bf16_t* gA = A + (size_t)m0 * K;
    const bf16_t* gB = Bw + (size_t)n0 * K;

    auto rdA = [&](int buf, int kh, int mf) -> bf16x8 {
        const int row = wr * 128 + mf * 16 + frow;
        return *(const bf16x8*)&smem[ABASE(buf, kh) + row * 32 + fchunk * 8];
    };
    auto rdB = [&](int buf, int kh, int nf) -> bf16x8 {
        const int row = wc * 64 + nf * 16 + frow;
        return *(const bf16x8*)&smem[BBASE(buf, kh) + row * 32 + fchunk * 8];
    };
    // one half-tile = 256 rows x 32 k-cols = 16 KB = 2 gl_lds per thread
    auto issueHalf = [&](const bf16_t* src, int dst) {
        gl_lds16(src + soff,                   smem + dst + (w << 9));
        gl_lds16(src + (size_t)128 * K + soff, smem + dst + 4096 + (w << 9));
    };

    f32x4 acc[8][4];
#pragma unroll
    for (int i = 0; i < 8; ++i)
#pragma unroll
        for (int j = 0; j < 4; ++j) acc[i][j] = (f32x4)0.0f;
    bf16x8 bfr[4];

    const int NT = K >> 6;

    // prologue halves h1..h6: A(0)k0, B(0)k0, A(0)k1, B(0)k1, A(1)k0, B(1)k0
    issueHalf(gA,      ABASE(0, 0));
    issueHalf(gB,      BBASE(0, 0));
    issueHalf(gA + 32, ABASE(0, 1));
    issueHalf(gB + 32, BBASE(0, 1));
    issueHalf(gA + 64, ABASE(1, 0));
    issueHalf(gB + 64, BBASE(1, 0));

    for (int t = 0; t < NT; ++t) {
        const int buf = t & 1;
        const bool s1 = (t + 1 < NT);
        const bool s2 = (t + 2 < NT);
        const bf16_t* aS1 = gA + (size_t)(t + 1) * 64 + 32;  // A(t+1) k1
        const bf16_t* bS1 = gB + (size_t)(t + 1) * 64 + 32;  // B(t+1) k1
        const bf16_t* aS2 = gA + (size_t)(t + 2) * 64;       // A(t+2) k0
        const bf16_t* bS2 = gB + (size_t)(t + 2) * 64;       // B(t+2) k0
        const int dA1 = ABASE((t + 1) & 1, 1);
        const int dB1 = BBASE((t + 1) & 1, 1);
        const int dA2 = ABASE(t & 1, 0);
        const int dB2 = BBASE(t & 1, 0);
        const int vq1 = (t == NT - 1) ? 4 : 8;
        const int vq3 = (t == NT - 1) ? 0 : 8;
        QP(buf, 0, 0, 1, s1, aS1, dA1, vq1);
        QP(buf, 1, 0, 0, s1, bS1, dB1, -1);
        QP(buf, 0, 1, 1, s2, aS2, dA2, vq3);
        QP(buf, 1, 1, 0, s2, bS2, dB2, -1);
    }
    barrier_mem();   // all reads done, no loads outstanding; smem reusable

    // C/D layout: col = lane&15, row = (lane>>4)*4 + reg
    const int crow = (lane >> 4) * 4;
    const int ccol = lane & 15;

    if (MODE == 0 && bz == 2) {
        // V projection: transposed store vT[b][n][s]
#pragma unroll
        for (int mt = 0; mt < 8; ++mt) {
            const int mb = m0 + wr * 128 + mt * 16 + crow;
#pragma unroll
            for (int nt = 0; nt < 4; ++nt) {
                const int n = n0 + wc * 64 + nt * 16 + ccol;
                const float bvv = bi[n];
                const int b = mb >> 11;      // S = 2048 tokens per batch
                const int s = mb & 2047;
                union { ushort4 u; bf16_t h[4]; } pk;
#pragma unroll
                for (int r = 0; r < 4; ++r) pk.h[r] = (__bf16)(acc[mt][nt][r] + bvv);
                *(ushort4*)&C2[(size_t)b * DHdim * Sdim + (size_t)n * Sdim + s] = pk.u;
            }
        }
        return;
    }

    // ---- transpose epilogue (per-wave 16x72 scratch, 8 waves = 18 KB) ----
    bf16_t* tw = smem + w * (16 * 72);
    const int r0 = lane >> 3;
    const int cseg = (lane & 7) * 8;

    float bv[4];
    if (MODE == 0) {
#pragma unroll
        for (int nt = 0; nt < 4; ++nt)
            bv[nt] = bi[n0 + wc * 64 + nt * 16 + ccol];
    }

#pragma unroll
    for (int mt = 0; mt < 8; ++mt) {
#pragma unroll
        for (int nt = 0; nt < 4; ++nt) {
            const float badd = (MODE == 0) ? bv[nt] : 0.0f;
#pragma unroll
            for (int r = 0; r < 4; ++r)
                tw[(crow + r) * 72 + nt * 16 + ccol] = (__bf16)(acc[mt][nt][r] + badd);
        }
        bf16x8 va = *(const bf16x8*)&tw[r0 * 72 + cseg];
        bf16x8 vb = *(const bf16x8*)&tw[(r0 + 8) * 72 + cseg];
        const int gm_a = m0 + wr * 128 + mt * 16 + r0;
        const int gm_b = gm_a + 8;
        const int gn = n0 + wc * 64 + cseg;
        *(bf16x8*)&C[(size_t)gm_a * N + gn] = va;
        *(bf16x8*)&C[(size_t)gm_b * N + gn] = vb;
    }
}

// Old generic NT GEMM (kept for PV / out-proj).
template <int MODE>
__global__ __launch_bounds__(512, 2)
void gemm_bt(const bf16_t* __restrict__ A, const bf16_t* __restrict__ Bw,
             const float* __restrict__ bias, const float* __restrict__ bias2,
             const float* __restrict__ bias3,
             bf16_t* __restrict__ C, bf16_t* __restrict__ C2,
             int M, int N, int K,
             long long sAz, long long sBz, long long sCz,
             const float* __restrict__ resid,
             int Sdim, int DHdim)
{
    const int bz = blockIdx.z;
    const float* bi = bias;
    if (MODE == 0) {
        Bw += (long long)bz * N * K;
        bi = (bz == 0) ? bias : (bz == 1 ? bias2 : bias3);
        if (bz < 2) C += (long long)bz * sCz;
    } else {
        A += (long long)bz * sAz;
        Bw += (long long)bz * sBz;
        C += (long long)bz * sCz;
    }
    const int num_n = N / BN;
    const int pid = blockIdx.x;
    const int group = 8 * num_n;
    const int g = pid / group;
    const int m0 = (g * 8 + (pid % 8)) * BM;
    const int n0 = ((pid % group) >> 3) * BN;

    const int tid = threadIdx.x;
    const int w = tid >> 6;
    const int lane = tid & 63;
    const int wr = w >> 1;
    const int wc = w & 1;
    const int frow = lane & 15;
    const int fchunk = lane >> 4;

    __shared__ bf16_t smem[NBUF * BUFELEMS];   // 144 KiB

    const int srow8 = lane >> 3;
    const int sch = (lane & 7) ^ srow8;
    const size_t soff = (size_t)(w * 8 + srow8) * K + ((size_t)sch << 3);
    const bf16_t* gA = A + (size_t)m0 * K;
    const bf16_t* gB = Bw + (size_t)n0 * K;

    auto stA = [&](int kt, int b, int i) {
        gl_lds16(gA + (size_t)(i * 64) * K + (size_t)kt * BK + soff,
                 smem + (size_t)b * BUFELEMS + (i * 64 + w * 8) * BK);
    };
    auto stB = [&](int kt, int b, int i) {
        gl_lds16(gB + (size_t)(i * 64) * K + (size_t)kt * BK + soff,
                 smem + (size_t)b * BUFELEMS + BM * BK + (i * 64 + w * 8) * BK);
    };

    f32x4 acc[4][4];
#pragma unroll
    for (int i = 0; i < 4; ++i)
#pragma unroll
        for (int j = 0; j < 4; ++j) acc[i][j] = (f32x4)0.0f;

    const int NT = K / BK;

#pragma unroll
    for (int i = 0; i < 4; ++i) stA(0, 0, i);
#pragma unroll
    for (int i = 0; i < 2; ++i) stB(0, 0, i);
#pragma unroll
    for (int i = 0; i < 4; ++i) stA(1, 1, i);
#pragma unroll
    for (int i = 0; i < 2; ++i) stB(1, 1, i);

    for (int kt = 0; kt < NT; ++kt) {
        const int cur = kt % NBUF;
        const int nxt = (kt + 2) % NBUF;
        const bool pf = (kt + 2 < NT);
        if (pf) { stA(kt + 2, nxt, 0); stA(kt + 2, nxt, 1); stA(kt + 2, nxt, 2); }
        if (pf)               asm volatile("s_waitcnt vmcnt(9)" ::: "memory");
        else if (kt + 1 < NT) asm volatile("s_waitcnt vmcnt(6)" ::: "memory");
        else                  asm volatile("s_waitcnt vmcnt(0)" ::: "memory");
        barrier_mem();

        const bf16_t* Ab = smem + (size_t)cur * BUFELEMS;
        const bf16_t* Bb = Ab + BM * BK;
        const int sw = frow & 7;

        bf16x8 af[4], b0v[2][2];
#pragma unroll
        for (int t = 0; t < 4; ++t) {
            const int row = wr * 64 + t * 16 + frow;
            af[t] = *(const bf16x8*)&Ab[row * BK + ((fchunk ^ sw) << 3)];
        }
        bf16x8 af1[4];
#pragma unroll
        for (int t = 0; t < 4; ++t) {
            const int row = wr * 64 + t * 16 + frow;
            af1[t] = *(const bf16x8*)&Ab[row * BK + (((4 + fchunk) ^ sw) << 3)];
        }
#pragma unroll
        for (int u = 0; u < 2; ++u) {
            const int row = wc * 64 + u * 16 + frow;
#pragma unroll
            for (int kh = 0; kh < 2; ++kh)
                b0v[u][kh] = *(const bf16x8*)&Bb[row * BK + (((kh * 4 + fchunk) ^ sw) << 3)];
        }
        if (pf) { stA(kt + 2, nxt, 3); stB(kt + 2, nxt, 0); stB(kt + 2, nxt, 1); }

        __builtin_amdgcn_s_setprio(1);
#pragma unroll
        for (int t = 0; t < 4; ++t)
#pragma unroll
            for (int u = 0; u < 2; ++u) {
                acc[t][u] = MFMA16(af[t], b0v[u][0], acc[t][u]);
                acc[t][u] = MFMA16(af1[t], b0v[u][1], acc[t][u]);
            }
        __builtin_amdgcn_s_setprio(0);

        bf16x8 b1v[2][2];
#pragma unroll
        for (int u = 0; u < 2; ++u) {
            const int row = wc * 64 + (u + 2) * 16 + frow;
#pragma unroll
            for (int kh = 0; kh < 2; ++kh)
                b1v[u][kh] = *(const bf16x8*)&Bb[row * BK + (((kh * 4 + fchunk) ^ sw) << 3)];
        }
        barrier_mem();

        __builtin_amdgcn_s_setprio(1);
#pragma unroll
        for (int t = 0; t < 4; ++t)
#pragma unroll
            for (int u = 0; u < 2; ++u) {
                acc[t][u + 2] = MFMA16(af[t], b1v[u][0], acc[t][u + 2]);
                acc[t][u + 2] = MFMA16(af1[t], b1v[u][1], acc[t][u + 2]);
            }
        __builtin_amdgcn_s_setprio(0);
        barrier_mem();
    }

    const int crow = (lane >> 4) * 4;
    const int ccol = lane & 15;

    bf16_t* tw = smem + w * (16 * 72);
    const int r0 = lane >> 3;
    const int cseg = (lane & 7) * 8;

    float bv[4];
    if (MODE == 4) {
#pragma unroll
        for (int nt = 0; nt < 4; ++nt)
            bv[nt] = bi[n0 + wc * 64 + nt * 16 + ccol];
    }

#pragma unroll
    for (int mt = 0; mt < 4; ++mt) {
#pragma unroll
        for (int nt = 0; nt < 4; ++nt) {
            const float badd = (MODE == 4) ? bv[nt] : 0.0f;
#pragma unroll
            for (int r = 0; r < 4; ++r)
                tw[(crow + r) * 72 + nt * 16 + ccol] = (__bf16)(acc[mt][nt][r] + badd);
        }
        bf16x8 va = *(const bf16x8*)&tw[r0 * 72 + cseg];
        bf16x8 vb = *(const bf16x8*)&tw[(r0 + 8) * 72 + cseg];

        const int gm_a = m0 + wr * 64 + mt * 16 + r0;
        const int gm_b = gm_a + 8;
        const int gn = n0 + wc * 64 + cseg;

        if (MODE == 3) {
            *(bf16x8*)&C[(size_t)gm_a * N + gn] = va;
            *(bf16x8*)&C[(size_t)gm_b * N + gn] = vb;
        } else {  // MODE 4: + residual, bf16 out
            const float4 xa0 = *(const float4*)&resid[(size_t)gm_a * N + gn];
            const float4 xa1 = *(const float4*)&resid[(size_t)gm_a * N + gn + 4];
            const float4 xb0 = *(const float4*)&resid[(size_t)gm_b * N + gn];
            const float4 xb1 = *(const float4*)&resid[(size_t)gm_b * N + gn + 4];
            bf16x8 oa, ob;
            oa[0] = (__bf16)((float)va[0] + xa0.x);
            oa[1] = (__bf16)((float)va[1] + xa0.y);
            oa[2] = (__bf16)((float)va[2] + xa0.z);
            oa[3] = (__bf16)((float)va[3] + xa0.w);
            oa[4] = (__bf16)((float)va[4] + xa1.x);
            oa[5] = (__bf16)((float)va[5] + xa1.y);
            oa[6] = (__bf16)((float)va[6] + xa1.z);
            oa[7] = (__bf16)((float)va[7] + xa1.w);
            ob[0] = (__bf16)((float)vb[0] + xb0.x);
            ob[1] = (__bf16)((float)vb[1] + xb0.y);
            ob[2] = (__bf16)((float)vb[2] + xb0.z);
            ob[3] = (__bf16)((float)vb[3] + xb0.w);
            ob[4] = (__bf16)((float)vb[4] + xb1.x);
            ob[5] = (__bf16)((float)vb[5] + xb1.y);
            ob[6] = (__bf16)((float)vb[6] + xb1.z);
            ob[7] = (__bf16)((float)vb[7] + xb1.w);
            *(bf16x8*)&C[(size_t)gm_a * N + gn] = oa;
            *(bf16x8*)&C[(size_t)gm_b * N + gn] = ob;
        }
    }
}

// Fused softmax over S=2048 (unchanged)
__global__ __launch_bounds__(256)
void softmax_kernel(bf16_t* __restrict__ sc, const int* __restrict__ rel,
                    const bf16_t* __restrict__ q, const float* __restrict__ de,
                    const float* __restrict__ mask)
{
    constexpr int S = 2048, H = 1024;
    const int row = blockIdx.x;
    const int b = row >> 11;
    const int tid = threadIdx.x;
    const int w = tid >> 6, lane = tid & 63;
    __shared__ float rd1[4], rmax[4], rsum[4];

    const bf16x4 q4 = *(const bf16x4*)(q + (size_t)row * H + tid * 4);
    const float4 e4 = *(const float4*)(de + H + tid * 4);
    float pd = (float)q4[0] * e4.x + (float)q4[1] * e4.y
             + (float)q4[2] * e4.z + (float)q4[3] * e4.w;
#pragma unroll
    for (int off = 32; off; off >>= 1) pd += __shfl_xor(pd, off, 64);
    if (lane == 0) rd1[w] = pd;
    __syncthreads();
    const float d1s = (rd1[0] + rd1[1] + rd1[2] + rd1[3]) * 0.03125f;

    bf16_t* p = sc + (size_t)row * S;
    const bf16x8 x = *(const bf16x8*)(p + tid * 8);
    const int4 rl0 = *(const int4*)&rel[(size_t)row * S + tid * 8];
    const int4 rl1 = *(const int4*)&rel[(size_t)row * S + tid * 8 + 4];
    const float4 mk0 = *(const float4*)&mask[(size_t)b * S + tid * 8];
    const float4 mk1 = *(const float4*)&mask[(size_t)b * S + tid * 8 + 4];
    const int rls[8] = {rl0.x, rl0.y, rl0.z, rl0.w, rl1.x, rl1.y, rl1.z, rl1.w};
    const float mks[8] = {mk0.x, mk0.y, mk0.z, mk0.w, mk1.x, mk1.y, mk1.z, mk1.w};
    float v[8];
    float mx = -1e30f;
#pragma unroll
    for (int j = 0; j < 8; ++j) {
        v[j] = (float)x[j] * 0.03125f + mks[j] + (rls[j] == 1 ? d1s : 0.0f);
        mx = fmaxf(mx, v[j]);
    }
#pragma unroll
    for (int off = 32; off; off >>= 1) mx = fmaxf(mx, __shfl_xor(mx, off, 64));
    if (lane == 0) rmax[w] = mx;
    __syncthreads();
    mx = fmaxf(fmaxf(rmax[0], rmax[1]), fmaxf(rmax[2], rmax[3]));
    float sum = 0.0f;
#pragma unroll
    for (int j = 0; j < 8; ++j) { v[j] = __expf(v[j] - mx); sum += v[j]; }
#pragma unroll
    for (int off = 32; off; off >>= 1) sum += __shfl_xor(sum, off, 64);
    if (lane == 0) rsum[w] = sum;
    __syncthreads();
    sum = rsum[0] + rsum[1] + rsum[2] + rsum[3];
    const float inv = 1.0f / sum;
    bf16x8 o;
#pragma unroll
    for (int j = 0; j < 8; ++j) o[j] = (__bf16)(v[j] * inv);
    *(bf16x8*)(p + tid * 8) = o;
}

// LayerNorm over H=1024 (unchanged)
__global__ __launch_bounds__(256)
void ln_kernel(const bf16_t* __restrict__ x, const float* __restrict__ gamma,
               const float* __restrict__ beta, float* __restrict__ out)
{
    const int H = 1024;
    const size_t row = blockIdx.x;
    const int tid = threadIdx.x;
    const int w = tid >> 6, lane = tid & 63;
    bf16x4 xv = *(const bf16x4*)(x + row * H + tid * 4);
    float v[4] = {(float)xv[0], (float)xv[1], (float)xv[2], (float)xv[3]};
    float s = 0.0f, s2 = 0.0f;
#pragma unroll
    for (int j = 0; j < 4; ++j) { s += v[j]; s2 += v[j] * v[j]; }
#pragma unroll
    for (int off = 32; off; off >>= 1) {
        s += __shfl_xor(s, off, 64);
        s2 += __shfl_xor(s2, off, 64);
    }
    __shared__ float rs[4], rs2[4];
    if (lane == 0) { rs[w] = s; rs2[w] = s2; }
    __syncthreads();
    s  = rs[0] + rs[1] + rs[2] + rs[3];
    s2 = rs2[0] + rs2[1] + rs2[2] + rs2[3];
    const float mu  = s * (1.0f / H);
    const float var = s2 * (1.0f / H) - mu * mu;
    const float inv = rsqrtf(var + 1e-12f);
    float4 o;
    const int c = tid * 4;
    o.x = (v[0] - mu) * inv * gamma[c + 0] + beta[c + 0];
    o.y = (v[1] - mu) * inv * gamma[c + 1] + beta[c + 1];
    o.z = (v[2] - mu) * inv * gamma[c + 2] + beta[c + 2];
    o.w = (v[3] - mu) * inv * gamma[c + 3] + beta[c + 3];
    *(float4*)(out + row * H + tid * 4) = o;
}

extern "C" void kernel_launch(void* const* d_in, const int* in_sizes, int n_in,
                              void* d_out, int out_size, void* d_ws, size_t ws_size,
                              hipStream_t stream)
{
    constexpr int B = 4, S = 2048, H = 1024;
    const float* hid = (const float*)d_in[0];
    const float* am  = (const float*)d_in[1];
    const int*   rel = (const int*)d_in[2];
    const float* Wq  = (const float*)d_in[3];
    const float* bq  = (const float*)d_in[4];
    const float* Wk  = (const float*)d_in[5];
    const float* bk  = (const float*)d_in[6];
    const float* Wv  = (const float*)d_in[7];
    const float* bv  = (const float*)d_in[8];
    const float* de  = (const float*)d_in[9];
    const float* Wo  = (const float*)d_in[10];
    const float* bo  = (const float*)d_in[11];
    const float* lng = (const float*)d_in[12];
    const float* lnb = (const float*)d_in[13];
    float* out = (float*)d_out;

    char* ws = (char*)d_ws;
    const int n_tok = B * S;                               // 8192
    const size_t MB = 1024 * 1024;
    bf16_t* hidb = (bf16_t*)(ws);                          // 16 MB
    bf16_t* Wqb  = (bf16_t*)(ws + 16 * MB);                // 2 MB each; contiguous
    bf16_t* Wob  = (bf16_t*)(ws + 22 * MB);
    bf16_t* qb   = (bf16_t*)(ws + 24 * MB);                // 16 MB; qb/kb contiguous
    bf16_t* kb   = (bf16_t*)(ws + 40 * MB);                // 16 MB
    bf16_t* vT   = (bf16_t*)(ws + 56 * MB);                // 16 MB (B, DH, S)
    bf16_t* ctx  = (bf16_t*)(ws + 72 * MB);                // 16 MB
    bf16_t* sc   = (bf16_t*)(ws + 88 * MB);                // 32 MB (B,S,S)
    bf16_t* xb   = (bf16_t*)(ws + 88 * MB);                // aliases sc

    const dim3 blk(256);
    const dim3 blkg(512);
    cvt_all_kernel<<<dim3(8192 + 4 * 1024), blk, 0, stream>>>(
        hid, Wq, Wk, Wv, Wo, hidb, Wqb);

    // Q + K + V projections: 8-phase 256x256 (32 m-tiles x 4 n-tiles, z=3)
    gemm8<0><<<dim3(32 * 4, 1, 3), blkg, 0, stream>>>(
        hidb, Wqb, bq, bk, bv, qb, vT, n_tok, H, H,
        0, 0, (long long)n_tok * H, S, H);
    // scores = q@k^T: 8-phase 256x256 (8x8 tiles, z=4 batches)
    gemm8<3><<<dim3(8 * 8, 1, B), blkg, 0, stream>>>(
        qb, kb, nullptr, nullptr, nullptr, sc, nullptr, S, S, H,
        (long long)S * H, (long long)S * H, (long long)S * S, S, H);
    softmax_kernel<<<dim3(B * S), blk, 0, stream>>>(sc, rel, qb, de, am);
    // ctx = probs @ v : 256x128 kernel (full occupancy at 256 blocks)
    gemm_bt<3><<<dim3((S / BM) * (H / BN), 1, B), blkg, 0, stream>>>(
        sc, vT, nullptr, nullptr, nullptr, ctx, nullptr, S, H, S,
        (long long)S * S, (long long)H * S, (long long)S * H,
        nullptr, S, H);
    // attn_out = ctx @ Wo^T + bo; x = attn_out + hidden
    gemm_bt<4><<<dim3((n_tok / BM) * (H / BN), 1, 1), blkg, 0, stream>>>(
        ctx, Wob, bo, nullptr, nullptr, xb, nullptr, n_tok, H, H, 0, 0, 0,
        hid, S, H);
    ln_kernel<<<dim3(n_tok), blk, 0, stream>>>(xb, lng, lnb, out);
}

// Round 6
// 342.398 us; speedup vs baseline: 1.0036x; 1.0036x over previous
//
#include <hip/hip_runtime.h>

// gemm_bt (scores / PV / out-proj): 256x128 tile, BK=64, 8 waves, 3-deep pipeline.
#define BM 256
#define BN 128
#define BK 64
#define NBUF 3
#define BUFELEMS ((BM + BN) * BK)   // bf16 elems per K-tile buffer (A then B)

typedef __bf16 bf16x8 __attribute__((ext_vector_type(8)));
typedef __bf16 bf16x4 __attribute__((ext_vector_type(4)));
typedef float f32x4 __attribute__((ext_vector_type(4)));
typedef __bf16 bf16_t;

#define MFMA16(a, b, c) __builtin_amdgcn_mfma_f32_16x16x32_bf16((a), (b), (c), 0, 0, 0)

__device__ __forceinline__ void gl_lds16(const void* g, void* l) {
    __builtin_amdgcn_global_load_lds(
        (const __attribute__((address_space(1))) void*)g,
        (__attribute__((address_space(3))) void*)l, 16, 0, 0);
}
// raw barrier with compiler memory fence: does NOT drain vmcnt
__device__ __forceinline__ void barrier_mem() {
    asm volatile("s_barrier" ::: "memory");
}

// fp32 -> bf16 conversion for hid + 4 weight matrices in ONE launch.
__global__ __launch_bounds__(256)
void cvt_all_kernel(const float* __restrict__ hid,
                    const float* __restrict__ w0, const float* __restrict__ w1,
                    const float* __restrict__ w2, const float* __restrict__ w3,
                    bf16_t* __restrict__ hidb, bf16_t* __restrict__ wb)
{
    const int bid = blockIdx.x;
    const float* src;
    bf16_t* dst;
    size_t off;
    if (bid < 8192) {
        src = hid; dst = hidb; off = (size_t)bid * 1024;
    } else {
        const int i = (bid - 8192) >> 10;
        src = (i == 0) ? w0 : (i == 1) ? w1 : (i == 2) ? w2 : w3;
        dst = wb + (size_t)i * 1024 * 1024;
        off = (size_t)((bid - 8192) & 1023) * 1024;
    }
    const size_t idx = off + threadIdx.x * 4;
    const float4 v = *(const float4*)(src + idx);
    bf16x4 o;
    o[0] = (__bf16)v.x; o[1] = (__bf16)v.y;
    o[2] = (__bf16)v.z; o[3] = (__bf16)v.w;
    *(bf16x4*)(dst + idx) = o;
}

// ---------------------------------------------------------------------------
// gemm128: high-occupancy 128x128 GEMM (m97-replica + counted vmcnt + swizzle).
// BK=32 K-steps, double-buffered LDS A0|A1|B0|B1 (8 KB each, 32 KB total) ->
// target 4 blocks/CU so cross-block waves fill barrier/LDS-latency stalls
// (m114 mechanism; this is the regime m97's 874 TF ran in).
// 256 threads = 4 waves (2m x 2n), 64x64 per wave, acc[4][4].
// Staging: 4 gl_lds/thread/K-step; linear LDS dest (base + lane*16), source
// 16B-chunk pre-swizzled by row bits1-2 (chunk ^= (row>>1)&3) -> reads are
// 2-way max bank aliasing (free, m136). Counted vmcnt(4): next K-step's 4
// loads stay in flight across the barrier; stage(kt+2) issued AFTER the
// closing barrier (its buffer just freed).
// MODE 0: QKV fused over z (z=2 -> vT transposed store). Same epilogues as R0.
// Requires num_m_tiles % 8 == 0, K % 64 == 0.
// ---------------------------------------------------------------------------
template <int MODE>
__global__ __launch_bounds__(256, 4)
void gemm128(const bf16_t* __restrict__ A, const bf16_t* __restrict__ Bw,
             const float* __restrict__ bias, const float* __restrict__ bias2,
             const float* __restrict__ bias3,
             bf16_t* __restrict__ C, bf16_t* __restrict__ C2,
             int M, int N, int K,
             long long sAz, long long sBz, long long sCz,
             const float* __restrict__ resid,
             int Sdim, int DHdim)
{
    const int bz = blockIdx.z;
    const float* bi = bias;
    if (MODE == 0) {
        Bw += (long long)bz * N * K;        // Wq | Wk | Wv contiguous
        bi = (bz == 0) ? bias : (bz == 1 ? bias2 : bias3);
        if (bz < 2) C += (long long)bz * sCz;
    } else {
        A += (long long)bz * sAz;
        Bw += (long long)bz * sBz;
        C += (long long)bz * sCz;
    }
    // grouped XCD-aware decode (GM=8) over 128x128 tiles
    const int num_n = N >> 7;
    const int pid = blockIdx.x;
    const int group = 8 * num_n;
    const int g = pid / group;
    const int m0 = (g * 8 + (pid % 8)) * 128;
    const int n0 = ((pid % group) >> 3) * 128;

    const int tid = threadIdx.x;
    const int w = tid >> 6;          // wave 0..3
    const int lane = tid & 63;
    const int wr = w >> 1;           // 2x2 wave grid, 64x64 each
    const int wc = w & 1;
    const int frow = lane & 15;
    const int fchunk = lane >> 4;    // 0..3 : 8-elem (16B) chunk of the 32-k row

    __shared__ bf16_t smem[16384];   // A0 | A1 | B0 | B1, 4096 elems (8 KB) each

    // staging map: thread t -> row t>>2 of a 64-row chunk, phys chunk t&3.
    // source chunk = (t&3) ^ (row bits1-2) = (t&3) ^ ((t>>3)&3).
    const size_t soff = (size_t)(tid >> 2) * K +
                        ((size_t)((tid & 3) ^ ((tid >> 3) & 3)) << 3);
    const bf16_t* gA = A + (size_t)m0 * K;
    const bf16_t* gB = Bw + (size_t)n0 * K;

    // one K-step = A 128x32 + B 128x32 = 4 gl_lds/thread
    auto stage = [&](int kt, int buf) {
        const size_t ko = (size_t)kt * 32;
        bf16_t* Ad = smem + buf * 4096;
        bf16_t* Bd = smem + 8192 + buf * 4096;
        gl_lds16(gA + ko + soff,                  Ad + (w << 9));
        gl_lds16(gA + ko + soff + (size_t)64 * K, Ad + 2048 + (w << 9));
        gl_lds16(gB + ko + soff,                  Bd + (w << 9));
        gl_lds16(gB + ko + soff + (size_t)64 * K, Bd + 2048 + (w << 9));
    };

    f32x4 acc[4][4];
#pragma unroll
    for (int i = 0; i < 4; ++i)
#pragma unroll
        for (int j = 0; j < 4; ++j) acc[i][j] = (f32x4)0.0f;

    const int NT = K >> 5;
    stage(0, 0);
    stage(1, 1);
    const int sw = (frow >> 1) & 3;   // read-side swizzle (row bits1-2)

    for (int kt = 0; kt < NT; ++kt) {
        const int buf = kt & 1;
        // drain tile kt's 4 loads (oldest); keep tile kt+1's in flight
        if (kt + 1 < NT) asm volatile("s_waitcnt vmcnt(4)" ::: "memory");
        else             asm volatile("s_waitcnt vmcnt(0)" ::: "memory");
        barrier_mem();                     // all waves' tile-kt data landed

        const bf16_t* Ab = smem + buf * 4096;
        const bf16_t* Bb = smem + 8192 + buf * 4096;
        bf16x8 af[4], bfv[4];
#pragma unroll
        for (int t = 0; t < 4; ++t)
            af[t] = *(const bf16x8*)&Ab[(wr * 64 + t * 16 + frow) * 32 +
                                        ((fchunk ^ sw) << 3)];
#pragma unroll
        for (int u = 0; u < 4; ++u)
            bfv[u] = *(const bf16x8*)&Bb[(wc * 64 + u * 16 + frow) * 32 +
                                         ((fchunk ^ sw) << 3)];
        __builtin_amdgcn_s_setprio(1);
#pragma unroll
        for (int mt = 0; mt < 4; ++mt)
#pragma unroll
            for (int nt = 0; nt < 4; ++nt)
                acc[mt][nt] = MFMA16(af[mt], bfv[nt], acc[mt][nt]);
        __builtin_amdgcn_s_setprio(0);
        barrier_mem();                     // all waves done reading buf
        if (kt + 2 < NT) stage(kt + 2, buf);
    }

    // C/D layout: col = lane&15, row = (lane>>4)*4 + reg
    const int crow = (lane >> 4) * 4;
    const int ccol = lane & 15;

    if (MODE == 0 && bz == 2) {
        // V projection: transposed store vT[b][n][s]
#pragma unroll
        for (int mt = 0; mt < 4; ++mt) {
            const int mb = m0 + wr * 64 + mt * 16 + crow;
#pragma unroll
            for (int nt = 0; nt < 4; ++nt) {
                const int n = n0 + wc * 64 + nt * 16 + ccol;
                const float bvv = bi[n];
                const int b = mb >> 11;      // S = 2048 tokens per batch
                const int s = mb & 2047;
                union { ushort4 u; bf16_t h[4]; } pk;
#pragma unroll
                for (int r = 0; r < 4; ++r) pk.h[r] = (__bf16)(acc[mt][nt][r] + bvv);
                *(ushort4*)&C2[(size_t)b * DHdim * Sdim + (size_t)n * Sdim + s] = pk.u;
            }
        }
        return;
    }

    // ---- transpose epilogue (per-wave 16x72 scratch, 4 waves = 9216 B) ----
    bf16_t* tw = smem + w * (16 * 72);
    const int r0 = lane >> 3;
    const int cseg = (lane & 7) * 8;

    float bv[4];
    if (MODE == 0 || MODE == 4) {
#pragma unroll
        for (int nt = 0; nt < 4; ++nt)
            bv[nt] = bi[n0 + wc * 64 + nt * 16 + ccol];
    }

#pragma unroll
    for (int mt = 0; mt < 4; ++mt) {
#pragma unroll
        for (int nt = 0; nt < 4; ++nt) {
            const float badd = (MODE == 0 || MODE == 4) ? bv[nt] : 0.0f;
#pragma unroll
            for (int r = 0; r < 4; ++r)
                tw[(crow + r) * 72 + nt * 16 + ccol] = (__bf16)(acc[mt][nt][r] + badd);
        }
        bf16x8 va = *(const bf16x8*)&tw[r0 * 72 + cseg];
        bf16x8 vb = *(const bf16x8*)&tw[(r0 + 8) * 72 + cseg];
        const int gm_a = m0 + wr * 64 + mt * 16 + r0;
        const int gm_b = gm_a + 8;
        const int gn = n0 + wc * 64 + cseg;

        if (MODE == 0 || MODE == 3) {
            *(bf16x8*)&C[(size_t)gm_a * N + gn] = va;
            *(bf16x8*)&C[(size_t)gm_b * N + gn] = vb;
        } else {  // MODE 4: + residual, bf16 out
            const float4 xa0 = *(const float4*)&resid[(size_t)gm_a * N + gn];
            const float4 xa1 = *(const float4*)&resid[(size_t)gm_a * N + gn + 4];
            const float4 xb0 = *(const float4*)&resid[(size_t)gm_b * N + gn];
            const float4 xb1 = *(const float4*)&resid[(size_t)gm_b * N + gn + 4];
            bf16x8 oa, ob;
            oa[0] = (__bf16)((float)va[0] + xa0.x);
            oa[1] = (__bf16)((float)va[1] + xa0.y);
            oa[2] = (__bf16)((float)va[2] + xa0.z);
            oa[3] = (__bf16)((float)va[3] + xa0.w);
            oa[4] = (__bf16)((float)va[4] + xa1.x);
            oa[5] = (__bf16)((float)va[5] + xa1.y);
            oa[6] = (__bf16)((float)va[6] + xa1.z);
            oa[7] = (__bf16)((float)va[7] + xa1.w);
            ob[0] = (__bf16)((float)vb[0] + xb0.x);
            ob[1] = (__bf16)((float)vb[1] + xb0.y);
            ob[2] = (__bf16)((float)vb[2] + xb0.z);
            ob[3] = (__bf16)((float)vb[3] + xb0.w);
            ob[4] = (__bf16)((float)vb[4] + xb1.x);
            ob[5] = (__bf16)((float)vb[5] + xb1.y);
            ob[6] = (__bf16)((float)vb[6] + xb1.z);
            ob[7] = (__bf16)((float)vb[7] + xb1.w);
            *(bf16x8*)&C[(size_t)gm_a * N + gn] = oa;
            *(bf16x8*)&C[(size_t)gm_b * N + gn] = ob;
        }
    }
}

// gemm_bt (R2-proven): 256x128, counted vmcnt depth-2, XOR swizzle, GM=8.
template <int MODE>
__global__ __launch_bounds__(512, 2)
void gemm_bt(const bf16_t* __restrict__ A, const bf16_t* __restrict__ Bw,
             const float* __restrict__ bias, const float* __restrict__ bias2,
             const float* __restrict__ bias3,
             bf16_t* __restrict__ C, bf16_t* __restrict__ C2,
             int M, int N, int K,
             long long sAz, long long sBz, long long sCz,
             const float* __restrict__ resid,
             int Sdim, int DHdim)
{
    const int bz = blockIdx.z;
    const float* bi = bias;
    if (MODE == 0) {
        Bw += (long long)bz * N * K;
        bi = (bz == 0) ? bias : (bz == 1 ? bias2 : bias3);
        if (bz < 2) C += (long long)bz * sCz;
    } else {
        A += (long long)bz * sAz;
        Bw += (long long)bz * sBz;
        C += (long long)bz * sCz;
    }
    const int num_n = N / BN;
    const int pid = blockIdx.x;
    const int group = 8 * num_n;
    const int g = pid / group;
    const int m0 = (g * 8 + (pid % 8)) * BM;
    const int n0 = ((pid % group) >> 3) * BN;

    const int tid = threadIdx.x;
    const int w = tid >> 6;
    const int lane = tid & 63;
    const int wr = w >> 1;
    const int wc = w & 1;
    const int frow = lane & 15;
    const int fchunk = lane >> 4;

    __shared__ bf16_t smem[NBUF * BUFELEMS];   // 144 KiB

    const int srow8 = lane >> 3;
    const int sch = (lane & 7) ^ srow8;
    const size_t soff = (size_t)(w * 8 + srow8) * K + ((size_t)sch << 3);
    const bf16_t* gA = A + (size_t)m0 * K;
    const bf16_t* gB = Bw + (size_t)n0 * K;

    auto stA = [&](int kt, int b, int i) {
        gl_lds16(gA + (size_t)(i * 64) * K + (size_t)kt * BK + soff,
                 smem + (size_t)b * BUFELEMS + (i * 64 + w * 8) * BK);
    };
    auto stB = [&](int kt, int b, int i) {
        gl_lds16(gB + (size_t)(i * 64) * K + (size_t)kt * BK + soff,
                 smem + (size_t)b * BUFELEMS + BM * BK + (i * 64 + w * 8) * BK);
    };

    f32x4 acc[4][4];
#pragma unroll
    for (int i = 0; i < 4; ++i)
#pragma unroll
        for (int j = 0; j < 4; ++j) acc[i][j] = (f32x4)0.0f;

    const int NT = K / BK;

#pragma unroll
    for (int i = 0; i < 4; ++i) stA(0, 0, i);
#pragma unroll
    for (int i = 0; i < 2; ++i) stB(0, 0, i);
#pragma unroll
    for (int i = 0; i < 4; ++i) stA(1, 1, i);
#pragma unroll
    for (int i = 0; i < 2; ++i) stB(1, 1, i);

    for (int kt = 0; kt < NT; ++kt) {
        const int cur = kt % NBUF;
        const int nxt = (kt + 2) % NBUF;
        const bool pf = (kt + 2 < NT);
        if (pf) { stA(kt + 2, nxt, 0); stA(kt + 2, nxt, 1); stA(kt + 2, nxt, 2); }
        if (pf)               asm volatile("s_waitcnt vmcnt(9)" ::: "memory");
        else if (kt + 1 < NT) asm volatile("s_waitcnt vmcnt(6)" ::: "memory");
        else                  asm volatile("s_waitcnt vmcnt(0)" ::: "memory");
        barrier_mem();

        const bf16_t* Ab = smem + (size_t)cur * BUFELEMS;
        const bf16_t* Bb = Ab + BM * BK;
        const int sw = frow & 7;

        bf16x8 af[4][2], b0v[2][2];
#pragma unroll
        for (int t = 0; t < 4; ++t) {
            const int row = wr * 64 + t * 16 + frow;
#pragma unroll
            for (int kh = 0; kh < 2; ++kh)
                af[t][kh] = *(const bf16x8*)&Ab[row * BK + (((kh * 4 + fchunk) ^ sw) << 3)];
        }
#pragma unroll
        for (int u = 0; u < 2; ++u) {
            const int row = wc * 64 + u * 16 + frow;
#pragma unroll
            for (int kh = 0; kh < 2; ++kh)
                b0v[u][kh] = *(const bf16x8*)&Bb[row * BK + (((kh * 4 + fchunk) ^ sw) << 3)];
        }
        if (pf) { stA(kt + 2, nxt, 3); stB(kt + 2, nxt, 0); stB(kt + 2, nxt, 1); }

        __builtin_amdgcn_s_setprio(1);
#pragma unroll
        for (int t = 0; t < 4; ++t)
#pragma unroll
            for (int u = 0; u < 2; ++u) {
                acc[t][u] = MFMA16(af[t][0], b0v[u][0], acc[t][u]);
                acc[t][u] = MFMA16(af[t][1], b0v[u][1], acc[t][u]);
            }
        __builtin_amdgcn_s_setprio(0);

        bf16x8 b1v[2][2];
#pragma unroll
        for (int u = 0; u < 2; ++u) {
            const int row = wc * 64 + (u + 2) * 16 + frow;
#pragma unroll
            for (int kh = 0; kh < 2; ++kh)
                b1v[u][kh] = *(const bf16x8*)&Bb[row * BK + (((kh * 4 + fchunk) ^ sw) << 3)];
        }
        barrier_mem();

        __builtin_amdgcn_s_setprio(1);
#pragma unroll
        for (int t = 0; t < 4; ++t)
#pragma unroll
            for (int u = 0; u < 2; ++u) {
                acc[t][u + 2] = MFMA16(af[t][0], b1v[u][0], acc[t][u + 2]);
                acc[t][u + 2] = MFMA16(af[t][1], b1v[u][1], acc[t][u + 2]);
            }
        __builtin_amdgcn_s_setprio(0);
        barrier_mem();
    }

    const int crow = (lane >> 4) * 4;
    const int ccol = lane & 15;

    if (MODE == 0 && bz == 2) {
#pragma unroll
        for (int mt = 0; mt < 4; ++mt) {
            const int mb = m0 + wr * 64 + mt * 16 + crow;
#pragma unroll
            for (int nt = 0; nt < 4; ++nt) {
                const int n = n0 + wc * 64 + nt * 16 + ccol;
                const float bvv = bi[n];
                const int b = mb >> 11;
                const int s = mb & 2047;
                union { ushort4 u; bf16_t h[4]; } pk;
#pragma unroll
                for (int r = 0; r < 4; ++r) pk.h[r] = (__bf16)(acc[mt][nt][r] + bvv);
                *(ushort4*)&C2[(size_t)b * DHdim * Sdim + (size_t)n * Sdim + s] = pk.u;
            }
        }
        return;
    }

    bf16_t* tw = smem + w * (16 * 72);
    const int r0 = lane >> 3;
    const int cseg = (lane & 7) * 8;

    float bv[4];
    if (MODE == 0 || MODE == 4) {
#pragma unroll
        for (int nt = 0; nt < 4; ++nt)
            bv[nt] = bi[n0 + wc * 64 + nt * 16 + ccol];
    }

#pragma unroll
    for (int mt = 0; mt < 4; ++mt) {
#pragma unroll
        for (int nt = 0; nt < 4; ++nt) {
            const float badd = (MODE == 0 || MODE == 4) ? bv[nt] : 0.0f;
#pragma unroll
            for (int r = 0; r < 4; ++r)
                tw[(crow + r) * 72 + nt * 16 + ccol] = (__bf16)(acc[mt][nt][r] + badd);
        }
        bf16x8 va = *(const bf16x8*)&tw[r0 * 72 + cseg];
        bf16x8 vb = *(const bf16x8*)&tw[(r0 + 8) * 72 + cseg];

        const int gm_a = m0 + wr * 64 + mt * 16 + r0;
        const int gm_b = gm_a + 8;
        const int gn = n0 + wc * 64 + cseg;

        if (MODE == 0 || MODE == 3) {
            *(bf16x8*)&C[(size_t)gm_a * N + gn] = va;
            *(bf16x8*)&C[(size_t)gm_b * N + gn] = vb;
        } else {
            const float4 xa0 = *(const float4*)&resid[(size_t)gm_a * N + gn];
            const float4 xa1 = *(const float4*)&resid[(size_t)gm_a * N + gn + 4];
            const float4 xb0 = *(const float4*)&resid[(size_t)gm_b * N + gn];
            const float4 xb1 = *(const float4*)&resid[(size_t)gm_b * N + gn + 4];
            bf16x8 oa, ob;
            oa[0] = (__bf16)((float)va[0] + xa0.x);
            oa[1] = (__bf16)((float)va[1] + xa0.y);
            oa[2] = (__bf16)((float)va[2] + xa0.z);
            oa[3] = (__bf16)((float)va[3] + xa0.w);
            oa[4] = (__bf16)((float)va[4] + xa1.x);
            oa[5] = (__bf16)((float)va[5] + xa1.y);
            oa[6] = (__bf16)((float)va[6] + xa1.z);
            oa[7] = (__bf16)((float)va[7] + xa1.w);
            ob[0] = (__bf16)((float)vb[0] + xb0.x);
            ob[1] = (__bf16)((float)vb[1] + xb0.y);
            ob[2] = (__bf16)((float)vb[2] + xb0.z);
            ob[3] = (__bf16)((float)vb[3] + xb0.w);
            ob[4] = (__bf16)((float)vb[4] + xb1.x);
            ob[5] = (__bf16)((float)vb[5] + xb1.y);
            ob[6] = (__bf16)((float)vb[6] + xb1.z);
            ob[7] = (__bf16)((float)vb[7] + xb1.w);
            *(bf16x8*)&C[(size_t)gm_a * N + gn] = oa;
            *(bf16x8*)&C[(size_t)gm_b * N + gn] = ob;
        }
    }
}

// Fused softmax over S=2048 (unchanged)
__global__ __launch_bounds__(256)
void softmax_kernel(bf16_t* __restrict__ sc, const int* __restrict__ rel,
                    const bf16_t* __restrict__ q, const float* __restrict__ de,
                    const float* __restrict__ mask)
{
    constexpr int S = 2048, H = 1024;
    const int row = blockIdx.x;
    const int b = row >> 11;
    const int tid = threadIdx.x;
    const int w = tid >> 6, lane = tid & 63;
    __shared__ float rd1[4], rmax[4], rsum[4];

    const bf16x4 q4 = *(const bf16x4*)(q + (size_t)row * H + tid * 4);
    const float4 e4 = *(const float4*)(de + H + tid * 4);
    float pd = (float)q4[0] * e4.x + (float)q4[1] * e4.y
             + (float)q4[2] * e4.z + (float)q4[3] * e4.w;
#pragma unroll
    for (int off = 32; off; off >>= 1) pd += __shfl_xor(pd, off, 64);
    if (lane == 0) rd1[w] = pd;
    __syncthreads();
    const float d1s = (rd1[0] + rd1[1] + rd1[2] + rd1[3]) * 0.03125f;

    bf16_t* p = sc + (size_t)row * S;
    const bf16x8 x = *(const bf16x8*)(p + tid * 8);
    const int4 rl0 = *(const int4*)&rel[(size_t)row * S + tid * 8];
    const int4 rl1 = *(const int4*)&rel[(size_t)row * S + tid * 8 + 4];
    const float4 mk0 = *(const float4*)&mask[(size_t)b * S + tid * 8];
    const float4 mk1 = *(const float4*)&mask[(size_t)b * S + tid * 8 + 4];
    const int rls[8] = {rl0.x, rl0.y, rl0.z, rl0.w, rl1.x, rl1.y, rl1.z, rl1.w};
    const float mks[8] = {mk0.x, mk0.y, mk0.z, mk0.w, mk1.x, mk1.y, mk1.z, mk1.w};
    float v[8];
    float mx = -1e30f;
#pragma unroll
    for (int j = 0; j < 8; ++j) {
        v[j] = (float)x[j] * 0.03125f + mks[j] + (rls[j] == 1 ? d1s : 0.0f);
        mx = fmaxf(mx, v[j]);
    }
#pragma unroll
    for (int off = 32; off; off >>= 1) mx = fmaxf(mx, __shfl_xor(mx, off, 64));
    if (lane == 0) rmax[w] = mx;
    __syncthreads();
    mx = fmaxf(fmaxf(rmax[0], rmax[1]), fmaxf(rmax[2], rmax[3]));
    float sum = 0.0f;
#pragma unroll
    for (int j = 0; j < 8; ++j) { v[j] = __expf(v[j] - mx); sum += v[j]; }
#pragma unroll
    for (int off = 32; off; off >>= 1) sum += __shfl_xor(sum, off, 64);
    if (lane == 0) rsum[w] = sum;
    __syncthreads();
    sum = rsum[0] + rsum[1] + rsum[2] + rsum[3];
    const float inv = 1.0f / sum;
    bf16x8 o;
#pragma unroll
    for (int j = 0; j < 8; ++j) o[j] = (__bf16)(v[j] * inv);
    *(bf16x8*)(p + tid * 8) = o;
}

// LayerNorm over H=1024 (unchanged)
__global__ __launch_bounds__(256)
void ln_kernel(const bf16_t* __restrict__ x, const float* __restrict__ gamma,
               const float* __restrict__ beta, float* __restrict__ out)
{
    const int H = 1024;
    const size_t row = blockIdx.x;
    const int tid = threadIdx.x;
    const int w = tid >> 6, lane = tid & 63;
    bf16x4 xv = *(const bf16x4*)(x + row * H + tid * 4);
    float v[4] = {(float)xv[0], (float)xv[1], (float)xv[2], (float)xv[3]};
    float s = 0.0f, s2 = 0.0f;
#pragma unroll
    for (int j = 0; j < 4; ++j) { s += v[j]; s2 += v[j] * v[j]; }
#pragma unroll
    for (int off = 32; off; off >>= 1) {
        s += __shfl_xor(s, off, 64);
        s2 += __shfl_xor(s2, off, 64);
    }
    __shared__ float rs[4], rs2[4];
    if (lane == 0) { rs[w] = s; rs2[w] = s2; }
    __syncthreads();
    s  = rs[0] + rs[1] + rs[2] + rs[3];
    s2 = rs2[0] + rs2[1] + rs2[2] + rs2[3];
    const float mu  = s * (1.0f / H);
    const float var = s2 * (1.0f / H) - mu * mu;
    const float inv = rsqrtf(var + 1e-12f);
    float4 o;
    const int c = tid * 4;
    o.x = (v[0] - mu) * inv * gamma[c + 0] + beta[c + 0];
    o.y = (v[1] - mu) * inv * gamma[c + 1] + beta[c + 1];
    o.z = (v[2] - mu) * inv * gamma[c + 2] + beta[c + 2];
    o.w = (v[3] - mu) * inv * gamma[c + 3] + beta[c + 3];
    *(float4*)(out + row * H + tid * 4) = o;
}

extern "C" void kernel_launch(void* const* d_in, const int* in_sizes, int n_in,
                              void* d_out, int out_size, void* d_ws, size_t ws_size,
                              hipStream_t stream)
{
    constexpr int B = 4, S = 2048, H = 1024;
    const float* hid = (const float*)d_in[0];
    const float* am  = (const float*)d_in[1];
    const int*   rel = (const int*)d_in[2];
    const float* Wq  = (const float*)d_in[3];
    const float* bq  = (const float*)d_in[4];
    const float* Wk  = (const float*)d_in[5];
    const float* bk  = (const float*)d_in[6];
    const float* Wv  = (const float*)d_in[7];
    const float* bv  = (const float*)d_in[8];
    const float* de  = (const float*)d_in[9];
    const float* Wo  = (const float*)d_in[10];
    const float* bo  = (const float*)d_in[11];
    const float* lng = (const float*)d_in[12];
    const float* lnb = (const float*)d_in[13];
    float* out = (float*)d_out;

    char* ws = (char*)d_ws;
    const int n_tok = B * S;                               // 8192
    const size_t MB = 1024 * 1024;
    bf16_t* hidb = (bf16_t*)(ws);                          // 16 MB
    bf16_t* Wqb  = (bf16_t*)(ws + 16 * MB);                // 2 MB each; contiguous
    bf16_t* Wob  = (bf16_t*)(ws + 22 * MB);
    bf16_t* qb   = (bf16_t*)(ws + 24 * MB);                // 16 MB; qb/kb contiguous
    bf16_t* kb   = (bf16_t*)(ws + 40 * MB);                // 16 MB
    bf16_t* vT   = (bf16_t*)(ws + 56 * MB);                // 16 MB (B, DH, S)
    bf16_t* ctx  = (bf16_t*)(ws + 72 * MB);                // 16 MB
    bf16_t* sc   = (bf16_t*)(ws + 88 * MB);                // 32 MB (B,S,S)
    bf16_t* xb   = (bf16_t*)(ws + 88 * MB);                // aliases sc

    const dim3 blk(256);
    const dim3 blkg(512);
    cvt_all_kernel<<<dim3(8192 + 4 * 1024), blk, 0, stream>>>(
        hid, Wq, Wk, Wv, Wo, hidb, Wqb);

    // Q + K + V projections: high-occupancy 128x128 (64 m-tiles x 8 n-tiles, z=3)
    gemm128<0><<<dim3(64 * 8, 1, 3), blk, 0, stream>>>(
        hidb, Wqb, bq, bk, bv, qb, vT, n_tok, H, H,
        0, 0, (long long)n_tok * H,
        nullptr, S, H);
    // scores = q@k^T
    gemm_bt<3><<<dim3((S / BM) * (S / BN), 1, B), blkg, 0, stream>>>(
        qb, kb, nullptr, nullptr, nullptr, sc, nullptr, S, S, H,
        (long long)S * H, (long long)S * H, (long long)S * S,
        nullptr, S, H);
    softmax_kernel<<<dim3(B * S), blk, 0, stream>>>(sc, rel, qb, de, am);
    // ctx = probs @ v
    gemm_bt<3><<<dim3((S / BM) * (H / BN), 1, B), blkg, 0, stream>>>(
        sc, vT, nullptr, nullptr, nullptr, ctx, nullptr, S, H, S,
        (long long)S * S, (long long)H * S, (long long)S * H,
        nullptr, S, H);
    // attn_out = ctx @ Wo^T + bo; x = attn_out + hidden
    gemm_bt<4><<<dim3((n_tok / BM) * (H / BN), 1, 1), blkg, 0, stream>>>(
        ctx, Wob, bo, nullptr, nullptr, xb, nullptr, n_tok, H, H, 0, 0, 0,
        hid, S, H);
    ln_kernel<<<dim3(n_tok), blk, 0, stream>>>(xb, lng, lnb, out);
}

// Round 9
// 326.211 us; speedup vs baseline: 1.0534x; 1.0496x over previous
//
#include <hip/hip_runtime.h>

// gemm_bt (all GEMMs): 256x128 tile, BK=64, 8 waves (4x2), 3-deep LDS pipeline,
// counted vmcnt (T3+T4), XOR bank swizzle (T2 both-sides), setprio (T5),
// XCD-aware grouped decode (T1, GM=8). Proven best: R2 @ 335.5us total.
#define BM 256
#define BN 128
#define BK 64
#define NBUF 3
#define BUFELEMS ((BM + BN) * BK)   // bf16 elems per K-tile buffer (A then B)

typedef __bf16 bf16x8 __attribute__((ext_vector_type(8)));
typedef __bf16 bf16x4 __attribute__((ext_vector_type(4)));
typedef float f32x4 __attribute__((ext_vector_type(4)));
typedef __bf16 bf16_t;

#define MFMA16(a, b, c) __builtin_amdgcn_mfma_f32_16x16x32_bf16((a), (b), (c), 0, 0, 0)

__device__ __forceinline__ void gl_lds16(const void* g, void* l) {
    __builtin_amdgcn_global_load_lds(
        (const __attribute__((address_space(1))) void*)g,
        (__attribute__((address_space(3))) void*)l, 16, 0, 0);
}
// raw barrier with compiler memory fence: does NOT drain vmcnt (that's the point)
__device__ __forceinline__ void barrier_mem() {
    asm volatile("s_barrier" ::: "memory");
}

// fp32 -> bf16 conversion for hid + 4 weight matrices in ONE launch.
// Extra tail blocks [12288, 12296) zero the d1 accumulator (8192 floats) —
// avoids any host-API call (hipMemsetAsync) inside kernel_launch.
__global__ __launch_bounds__(256)
void cvt_all_kernel(const float* __restrict__ hid,
                    const float* __restrict__ w0, const float* __restrict__ w1,
                    const float* __restrict__ w2, const float* __restrict__ w3,
                    bf16_t* __restrict__ hidb, bf16_t* __restrict__ wb,
                    float* __restrict__ d1g)
{
    const int bid = blockIdx.x;
    if (bid >= 12288) {
        const int i = (bid - 12288) * 1024 + threadIdx.x * 4;
        *(float4*)(d1g + i) = make_float4(0.f, 0.f, 0.f, 0.f);
        return;
    }
    const float* src;
    bf16_t* dst;
    size_t off;
    if (bid < 8192) {
        src = hid; dst = hidb; off = (size_t)bid * 1024;
    } else {
        const int i = (bid - 8192) >> 10;
        src = (i == 0) ? w0 : (i == 1) ? w1 : (i == 2) ? w2 : w3;
        dst = wb + (size_t)i * 1024 * 1024;
        off = (size_t)((bid - 8192) & 1023) * 1024;
    }
    const size_t idx = off + threadIdx.x * 4;
    const float4 v = *(const float4*)(src + idx);
    bf16x4 o;
    o[0] = (__bf16)v.x; o[1] = (__bf16)v.y;
    o[2] = (__bf16)v.z; o[3] = (__bf16)v.w;
    *(bf16x4*)(dst + idx) = o;
}

// Generic NT GEMM: C[m,n] = sum_k A[m,k] * Bw[n,k]  (+ epilogue per MODE)
// MODE 0: QKV fused over z: z=0 -> Wq/bq (+ d1 atomic dot with de1);
//         z=1 -> Wk/bk; z=2 -> Wv/bv transposed into vT
// MODE 3: plain bf16 store, batched z                  [scores, PV]
// MODE 4: + bias[n] + resid[m,n], bf16 out             [out-proj + residual]
// d1[row] = sum_col q[row][col]*de1[col], accumulated via atomics from the
// z=0 epilogue (8-lane shuffle reduce per row-slice; d1 zeroed in cvt launch).
template <int MODE>
__global__ __launch_bounds__(512, 2)
void gemm_bt(const bf16_t* __restrict__ A, const bf16_t* __restrict__ Bw,
             const float* __restrict__ bias, const float* __restrict__ bias2,
             const float* __restrict__ bias3,
             bf16_t* __restrict__ C, bf16_t* __restrict__ C2,
             int M, int N, int K,
             long long sAz, long long sBz, long long sCz,
             const float* __restrict__ resid,
             int Sdim, int DHdim,
             const float* __restrict__ deg, float* __restrict__ d1g)
{
    const int bz = blockIdx.z;
    const float* bi = bias;
    if (MODE == 0) {
        Bw += (long long)bz * N * K;        // Wq | Wk | Wv contiguous
        bi = (bz == 0) ? bias : (bz == 1 ? bias2 : bias3);
        if (bz < 2) C += (long long)bz * sCz;
    } else {
        A += (long long)bz * sAz;
        Bw += (long long)bz * sBz;
        C += (long long)bz * sCz;
    }
    // grouped XCD-aware decode (GM=8)
    const int num_n = N / BN;
    const int pid = blockIdx.x;
    const int group = 8 * num_n;
    const int g = pid / group;
    const int m0 = (g * 8 + (pid % 8)) * BM;
    const int n0 = ((pid % group) >> 3) * BN;

    const int tid = threadIdx.x;
    const int w = tid >> 6;
    const int lane = tid & 63;
    const int wr = w >> 1;
    const int wc = w & 1;
    const int frow = lane & 15;
    const int fchunk = lane >> 4;

    __shared__ bf16_t smem[NBUF * BUFELEMS];   // 144 KiB

    const int srow8 = lane >> 3;
    const int sch = (lane & 7) ^ srow8;
    const size_t soff = (size_t)(w * 8 + srow8) * K + ((size_t)sch << 3);
    const bf16_t* gA = A + (size_t)m0 * K;
    const bf16_t* gB = Bw + (size_t)n0 * K;

    auto stA = [&](int kt, int b, int i) {
        gl_lds16(gA + (size_t)(i * 64) * K + (size_t)kt * BK + soff,
                 smem + (size_t)b * BUFELEMS + (i * 64 + w * 8) * BK);
    };
    auto stB = [&](int kt, int b, int i) {
        gl_lds16(gB + (size_t)(i * 64) * K + (size_t)kt * BK + soff,
                 smem + (size_t)b * BUFELEMS + BM * BK + (i * 64 + w * 8) * BK);
    };

    f32x4 acc[4][4];
#pragma unroll
    for (int i = 0; i < 4; ++i)
#pragma unroll
        for (int j = 0; j < 4; ++j) acc[i][j] = (f32x4)0.0f;

    const int NT = K / BK;

#pragma unroll
    for (int i = 0; i < 4; ++i) stA(0, 0, i);
#pragma unroll
    for (int i = 0; i < 2; ++i) stB(0, 0, i);
#pragma unroll
    for (int i = 0; i < 4; ++i) stA(1, 1, i);
#pragma unroll
    for (int i = 0; i < 2; ++i) stB(1, 1, i);

    for (int kt = 0; kt < NT; ++kt) {
        const int cur = kt % NBUF;
        const int nxt = (kt + 2) % NBUF;
        const bool pf = (kt + 2 < NT);
        if (pf) { stA(kt + 2, nxt, 0); stA(kt + 2, nxt, 1); stA(kt + 2, nxt, 2); }
        if (pf)               asm volatile("s_waitcnt vmcnt(9)" ::: "memory");
        else if (kt + 1 < NT) asm volatile("s_waitcnt vmcnt(6)" ::: "memory");
        else                  asm volatile("s_waitcnt vmcnt(0)" ::: "memory");
        barrier_mem();

        const bf16_t* Ab = smem + (size_t)cur * BUFELEMS;
        const bf16_t* Bb = Ab + BM * BK;
        const int sw = frow & 7;

        bf16x8 af[4][2], b0v[2][2];
#pragma unroll
        for (int t = 0; t < 4; ++t) {
            const int row = wr * 64 + t * 16 + frow;
#pragma unroll
            for (int kh = 0; kh < 2; ++kh)
                af[t][kh] = *(const bf16x8*)&Ab[row * BK + (((kh * 4 + fchunk) ^ sw) << 3)];
        }
#pragma unroll
        for (int u = 0; u < 2; ++u) {
            const int row = wc * 64 + u * 16 + frow;
#pragma unroll
            for (int kh = 0; kh < 2; ++kh)
                b0v[u][kh] = *(const bf16x8*)&Bb[row * BK + (((kh * 4 + fchunk) ^ sw) << 3)];
        }
        if (pf) { stA(kt + 2, nxt, 3); stB(kt + 2, nxt, 0); stB(kt + 2, nxt, 1); }

        __builtin_amdgcn_s_setprio(1);
#pragma unroll
        for (int t = 0; t < 4; ++t)
#pragma unroll
            for (int u = 0; u < 2; ++u) {
                acc[t][u] = MFMA16(af[t][0], b0v[u][0], acc[t][u]);
                acc[t][u] = MFMA16(af[t][1], b0v[u][1], acc[t][u]);
            }
        __builtin_amdgcn_s_setprio(0);

        bf16x8 b1v[2][2];
#pragma unroll
        for (int u = 0; u < 2; ++u) {
            const int row = wc * 64 + (u + 2) * 16 + frow;
#pragma unroll
            for (int kh = 0; kh < 2; ++kh)
                b1v[u][kh] = *(const bf16x8*)&Bb[row * BK + (((kh * 4 + fchunk) ^ sw) << 3)];
        }
        barrier_mem();

        __builtin_amdgcn_s_setprio(1);
#pragma unroll
        for (int t = 0; t < 4; ++t)
#pragma unroll
            for (int u = 0; u < 2; ++u) {
                acc[t][u + 2] = MFMA16(af[t][0], b1v[u][0], acc[t][u + 2]);
                acc[t][u + 2] = MFMA16(af[t][1], b1v[u][1], acc[t][u + 2]);
            }
        __builtin_amdgcn_s_setprio(0);
        barrier_mem();
    }
    // After the final barrier all LDS reads are drained; smem reusable.

    // C/D layout: col = lane&15, row = (lane>>4)*4 + reg
    const int crow = (lane >> 4) * 4;
    const int ccol = lane & 15;

    if (MODE == 0 && bz == 2) {
        // V projection: transposed store vT[b][n][s]
#pragma unroll
        for (int mt = 0; mt < 4; ++mt) {
            const int mb = m0 + wr * 64 + mt * 16 + crow;
#pragma unroll
            for (int nt = 0; nt < 4; ++nt) {
                const int n = n0 + wc * 64 + nt * 16 + ccol;
                const float bvv = bi[n];
                const int b = mb >> 11;      // S = 2048 tokens per batch
                const int s = mb & 2047;
                union { ushort4 u; bf16_t h[4]; } pk;
#pragma unroll
                for (int r = 0; r < 4; ++r) pk.h[r] = (__bf16)(acc[mt][nt][r] + bvv);
                *(ushort4*)&C2[(size_t)b * DHdim * Sdim + (size_t)n * Sdim + s] = pk.u;
            }
        }
        return;
    }

    // ---- transpose epilogue ----
    bf16_t* tw = smem + w * (16 * 72);
    const int r0 = lane >> 3;            // 0..7 : row within 16-slice
    const int cseg = (lane & 7) * 8;     // 8-col segment base

    float bv[4];
    if (MODE == 0 || MODE == 4) {
#pragma unroll
        for (int nt = 0; nt < 4; ++nt)
            bv[nt] = bi[n0 + wc * 64 + nt * 16 + ccol];
    }

#pragma unroll
    for (int mt = 0; mt < 4; ++mt) {
        // scatter this wave's 16x64 slice into LDS (same-wave DS is in-order)
#pragma unroll
        for (int nt = 0; nt < 4; ++nt) {
            const float badd = (MODE == 0 || MODE == 4) ? bv[nt] : 0.0f;
#pragma unroll
            for (int r = 0; r < 4; ++r)
                tw[(crow + r) * 72 + nt * 16 + ccol] = (__bf16)(acc[mt][nt][r] + badd);
        }
        bf16x8 va = *(const bf16x8*)&tw[r0 * 72 + cseg];
        bf16x8 vb = *(const bf16x8*)&tw[(r0 + 8) * 72 + cseg];

        const int gm_a = m0 + wr * 64 + mt * 16 + r0;
        const int gm_b = gm_a + 8;
        const int gn = n0 + wc * 64 + cseg;

        if (MODE == 0 || MODE == 3) {
            *(bf16x8*)&C[(size_t)gm_a * N + gn] = va;
            *(bf16x8*)&C[(size_t)gm_b * N + gn] = vb;
            // d1[row] += q[row, gn..gn+7] . de1[gn..gn+7]  (z=0 only)
            if (MODE == 0 && bz == 0) {
                const float4 e0 = *(const float4*)&deg[gn];
                const float4 e1 = *(const float4*)&deg[gn + 4];
                float pa = (float)va[0] * e0.x + (float)va[1] * e0.y
                         + (float)va[2] * e0.z + (float)va[3] * e0.w
                         + (float)va[4] * e1.x + (float)va[5] * e1.y
                         + (float)va[6] * e1.z + (float)va[7] * e1.w;
                float pb = (float)vb[0] * e0.x + (float)vb[1] * e0.y
                         + (float)vb[2] * e0.z + (float)vb[3] * e0.w
                         + (float)vb[4] * e1.x + (float)vb[5] * e1.y
                         + (float)vb[6] * e1.z + (float)vb[7] * e1.w;
                // reduce over the 8 lanes (lane&7) sharing this row
                pa += __shfl_xor(pa, 1, 64); pa += __shfl_xor(pa, 2, 64);
                pa += __shfl_xor(pa, 4, 64);
                pb += __shfl_xor(pb, 1, 64); pb += __shfl_xor(pb, 2, 64);
                pb += __shfl_xor(pb, 4, 64);
                if ((lane & 7) == 0) {
                    atomicAdd(&d1g[gm_a], pa);
                    atomicAdd(&d1g[gm_b], pb);
                }
            }
        } else {  // MODE 4: + residual, bf16 out
            const float4 xa0 = *(const float4*)&resid[(size_t)gm_a * N + gn];
            const float4 xa1 = *(const float4*)&resid[(size_t)gm_a * N + gn + 4];
            const float4 xb0 = *(const float4*)&resid[(size_t)gm_b * N + gn];
            const float4 xb1 = *(const float4*)&resid[(size_t)gm_b * N + gn + 4];
            bf16x8 oa, ob;
            oa[0] = (__bf16)((float)va[0] + xa0.x);
            oa[1] = (__bf16)((float)va[1] + xa0.y);
            oa[2] = (__bf16)((float)va[2] + xa0.z);
            oa[3] = (__bf16)((float)va[3] + xa0.w);
            oa[4] = (__bf16)((float)va[4] + xa1.x);
            oa[5] = (__bf16)((float)va[5] + xa1.y);
            oa[6] = (__bf16)((float)va[6] + xa1.z);
            oa[7] = (__bf16)((float)va[7] + xa1.w);
            ob[0] = (__bf16)((float)vb[0] + xb0.x);
            ob[1] = (__bf16)((float)vb[1] + xb0.y);
            ob[2] = (__bf16)((float)vb[2] + xb0.z);
            ob[3] = (__bf16)((float)vb[3] + xb0.w);
            ob[4] = (__bf16)((float)vb[4] + xb1.x);
            ob[5] = (__bf16)((float)vb[5] + xb1.y);
            ob[6] = (__bf16)((float)vb[6] + xb1.z);
            ob[7] = (__bf16)((float)vb[7] + xb1.w);
            *(bf16x8*)&C[(size_t)gm_a * N + gn] = oa;
            *(bf16x8*)&C[(size_t)gm_b * N + gn] = ob;
        }
    }
}

// Fused softmax over S=2048: d1 precomputed by QKV epilogue; per element
// v = s/32 + mask + (rel==1 ? d1/32 : 0), max/exp/sum, writes probs.
__global__ __launch_bounds__(256)
void softmax_kernel(bf16_t* __restrict__ sc, const int* __restrict__ rel,
                    const float* __restrict__ d1g, const float* __restrict__ mask)
{
    constexpr int S = 2048;
    const int row = blockIdx.x;
    const int b = row >> 11;             // 2048 rows per batch
    const int tid = threadIdx.x;
    const int w = tid >> 6, lane = tid & 63;
    __shared__ float rmax[4], rsum[4];

    const float d1s = d1g[row] * 0.03125f;

    bf16_t* p = sc + (size_t)row * S;
    const bf16x8 x = *(const bf16x8*)(p + tid * 8);
    const int4 rl0 = *(const int4*)&rel[(size_t)row * S + tid * 8];
    const int4 rl1 = *(const int4*)&rel[(size_t)row * S + tid * 8 + 4];
    const float4 mk0 = *(const float4*)&mask[(size_t)b * S + tid * 8];
    const float4 mk1 = *(const float4*)&mask[(size_t)b * S + tid * 8 + 4];
    const int rls[8] = {rl0.x, rl0.y, rl0.z, rl0.w, rl1.x, rl1.y, rl1.z, rl1.w};
    const float mks[8] = {mk0.x, mk0.y, mk0.z, mk0.w, mk1.x, mk1.y, mk1.z, mk1.w};
    float v[8];
    float mx = -1e30f;
#pragma unroll
    for (int j = 0; j < 8; ++j) {
        v[j] = (float)x[j] * 0.03125f + mks[j] + (rls[j] == 1 ? d1s : 0.0f);
        mx = fmaxf(mx, v[j]);
    }
#pragma unroll
    for (int off = 32; off; off >>= 1) mx = fmaxf(mx, __shfl_xor(mx, off, 64));
    if (lane == 0) rmax[w] = mx;
    __syncthreads();
    mx = fmaxf(fmaxf(rmax[0], rmax[1]), fmaxf(rmax[2], rmax[3]));
    float sum = 0.0f;
#pragma unroll
    for (int j = 0; j < 8; ++j) { v[j] = __expf(v[j] - mx); sum += v[j]; }
#pragma unroll
    for (int off = 32; off; off >>= 1) sum += __shfl_xor(sum, off, 64);
    if (lane == 0) rsum[w] = sum;
    __syncthreads();
    sum = rsum[0] + rsum[1] + rsum[2] + rsum[3];
    const float inv = 1.0f / sum;
    bf16x8 o;
#pragma unroll
    for (int j = 0; j < 8; ++j) o[j] = (__bf16)(v[j] * inv);
    *(bf16x8*)(p + tid * 8) = o;
}

// LayerNorm over H=1024, bf16 in / fp32 out, one block per row
__global__ __launch_bounds__(256)
void ln_kernel(const bf16_t* __restrict__ x, const float* __restrict__ gamma,
               const float* __restrict__ beta, float* __restrict__ out)
{
    const int H = 1024;
    const size_t row = blockIdx.x;
    const int tid = threadIdx.x;
    const int w = tid >> 6, lane = tid & 63;
    bf16x4 xv = *(const bf16x4*)(x + row * H + tid * 4);
    float v[4] = {(float)xv[0], (float)xv[1], (float)xv[2], (float)xv[3]};
    float s = 0.0f, s2 = 0.0f;
#pragma unroll
    for (int j = 0; j < 4; ++j) { s += v[j]; s2 += v[j] * v[j]; }
#pragma unroll
    for (int off = 32; off; off >>= 1) {
        s += __shfl_xor(s, off, 64);
        s2 += __shfl_xor(s2, off, 64);
    }
    __shared__ float rs[4], rs2[4];
    if (lane == 0) { rs[w] = s; rs2[w] = s2; }
    __syncthreads();
    s  = rs[0] + rs[1] + rs[2] + rs[3];
    s2 = rs2[0] + rs2[1] + rs2[2] + rs2[3];
    const float mu  = s * (1.0f / H);
    const float var = s2 * (1.0f / H) - mu * mu;
    const float inv = rsqrtf(var + 1e-12f);
    float4 o;
    const int c = tid * 4;
    o.x = (v[0] - mu) * inv * gamma[c + 0] + beta[c + 0];
    o.y = (v[1] - mu) * inv * gamma[c + 1] + beta[c + 1];
    o.z = (v[2] - mu) * inv * gamma[c + 2] + beta[c + 2];
    o.w = (v[3] - mu) * inv * gamma[c + 3] + beta[c + 3];
    *(float4*)(out + row * H + tid * 4) = o;
}

extern "C" void kernel_launch(void* const* d_in, const int* in_sizes, int n_in,
                              void* d_out, int out_size, void* d_ws, size_t ws_size,
                              hipStream_t stream)
{
    constexpr int B = 4, S = 2048, H = 1024;
    const float* hid = (const float*)d_in[0];
    const float* am  = (const float*)d_in[1];
    const int*   rel = (const int*)d_in[2];
    const float* Wq  = (const float*)d_in[3];
    const float* bq  = (const float*)d_in[4];
    const float* Wk  = (const float*)d_in[5];
    const float* bk  = (const float*)d_in[6];
    const float* Wv  = (const float*)d_in[7];
    const float* bv  = (const float*)d_in[8];
    const float* de  = (const float*)d_in[9];
    const float* Wo  = (const float*)d_in[10];
    const float* bo  = (const float*)d_in[11];
    const float* lng = (const float*)d_in[12];
    const float* lnb = (const float*)d_in[13];
    float* out = (float*)d_out;

    char* ws = (char*)d_ws;
    const int n_tok = B * S;                               // 8192
    const size_t MB = 1024 * 1024;
    bf16_t* hidb = (bf16_t*)(ws);                          // 16 MB
    bf16_t* Wqb  = (bf16_t*)(ws + 16 * MB);                // 2 MB each; contiguous
    bf16_t* Wob  = (bf16_t*)(ws + 22 * MB);
    bf16_t* qb   = (bf16_t*)(ws + 24 * MB);                // 16 MB; qb/kb contiguous
    bf16_t* kb   = (bf16_t*)(ws + 40 * MB);                // 16 MB
    bf16_t* vT   = (bf16_t*)(ws + 56 * MB);                // 16 MB (B, DH, S)
    bf16_t* ctx  = (bf16_t*)(ws + 72 * MB);                // 16 MB
    bf16_t* sc   = (bf16_t*)(ws + 88 * MB);                // 32 MB (B,S,S)
    bf16_t* xb   = (bf16_t*)(ws + 88 * MB);                // aliases sc (dead after PV)
    // d1[8192] f32 aliases the START of ctx: written by QKV, read by softmax,
    // both strictly before PV writes ctx. Stream-ordered -> safe.
    float* d1    = (float*)(ws + 72 * MB);

    const dim3 blk(256);
    const dim3 blkg(512);
    // hid + weights fp32->bf16, plus d1 zeroing in the 8 tail blocks
    cvt_all_kernel<<<dim3(8192 + 4 * 1024 + 8), blk, 0, stream>>>(
        hid, Wq, Wk, Wv, Wo, hidb, Wqb, d1);

    // Q + K + V projections fused over z (+ d1 atomic dot in z=0 epilogue)
    gemm_bt<0><<<dim3((n_tok / BM) * (H / BN), 1, 3), blkg, 0, stream>>>(
        hidb, Wqb, bq, bk, bv, qb, vT, n_tok, H, H,
        0, 0, (long long)n_tok * H,
        nullptr, S, H, de + H, d1);
    // scores = q@k^T  (pure GEMM; rel/d1/scale/mask applied in softmax)
    gemm_bt<3><<<dim3((S / BM) * (S / BN), 1, B), blkg, 0, stream>>>(
        qb, kb, nullptr, nullptr, nullptr, sc, nullptr, S, S, H,
        (long long)S * H, (long long)S * H, (long long)S * S,
        nullptr, S, H, nullptr, nullptr);
    softmax_kernel<<<dim3(B * S), blk, 0, stream>>>(sc, rel, d1, am);
    // ctx = probs @ v
    gemm_bt<3><<<dim3((S / BM) * (H / BN), 1, B), blkg, 0, stream>>>(
        sc, vT, nullptr, nullptr, nullptr, ctx, nullptr, S, H, S,
        (long long)S * S, (long long)H * S, (long long)S * H,
        nullptr, S, H, nullptr, nullptr);
    // attn_out = ctx @ Wo^T + bo; x = attn_out + hidden
    gemm_bt<4><<<dim3((n_tok / BM) * (H / BN), 1, 1), blkg, 0, stream>>>(
        ctx, Wob, bo, nullptr, nullptr, xb, nullptr, n_tok, H, H, 0, 0, 0,
        hid, S, H, nullptr, nullptr);
    ln_kernel<<<dim3(n_tok), blk, 0, stream>>>(xb, lng, lnb, out);
}